// Round 11
// baseline (323.401 us; speedup 1.0000x reference)
//
#include <hip/hip_runtime.h>
#include <hip/hip_bf16.h>

#define NN 100000
#define NE 1600000
#define DD 64
#define CAP 48      // max in-degree slots per node
#define NB 500      // buckets
#define BSZ 200     // nodes per bucket (NB*BSZ == NN)
#define CAPB 4224   // edge capacity per bucket (mean 3200, +18 sigma)
#define EPB 6400    // edges per block in pass A (250 blocks, 1024 threads)
#define ABD 1024    // binA block dim

typedef __bf16 bf16x8 __attribute__((ext_vector_type(8)));
typedef float f32x4 __attribute__((ext_vector_type(4)));
typedef int   i32x4 __attribute__((ext_vector_type(4)));

// ---------------- pass A: bin edges by dst-bucket (and srcs by src-bucket) ----------------
// Edge chunk staged in LDS (single global read of ei); stream writes are non-temporal.

__global__ __launch_bounds__(ABD) void binA_kernel(const int* __restrict__ ei,
    int* __restrict__ gcd, int* __restrict__ gcs,
    unsigned* __restrict__ bind, int* __restrict__ bins) {
  __shared__ int hd[NB], hs[NB], bd[NB], bs[NB];
  __shared__ int les[EPB], led[EPB];     // 51.2 KB edge stage
  int e0 = blockIdx.x * EPB;
  for (int i = threadIdx.x; i < NB; i += ABD) { hd[i] = 0; hs[i] = 0; }
  __syncthreads();
  for (int i = threadIdx.x; i < EPB; i += ABD) {
    int e = e0 + i;
    int s = __builtin_nontemporal_load(ei + e);
    int d = __builtin_nontemporal_load(ei + NE + e);
    les[i] = s; led[i] = d;
    if (s != d) { atomicAdd(&hs[s / BSZ], 1); atomicAdd(&hd[d / BSZ], 1); }
  }
  __syncthreads();
  for (int i = threadIdx.x; i < NB; i += ABD) {
    bd[i] = atomicAdd(&gcd[i], hd[i]);
    bs[i] = atomicAdd(&gcs[i], hs[i]);
  }
  __syncthreads();
  for (int i = threadIdx.x; i < NB; i += ABD) { hd[i] = 0; hs[i] = 0; }
  __syncthreads();
  for (int i = threadIdx.x; i < EPB; i += ABD) {
    int s = les[i], d = led[i];
    if (s == d) continue;
    int b = d / BSZ;
    int p = atomicAdd(&hd[b], 1);
    unsigned idx = (unsigned)(bd[b] + p);
    if (idx < CAPB)
      __builtin_nontemporal_store(((unsigned)s << 8) | (unsigned)(d - b * BSZ),
                                  bind + (size_t)b * CAPB + idx);
    int b2 = s / BSZ;
    int p2 = atomicAdd(&hs[b2], 1);
    unsigned idx2 = (unsigned)(bs[b2] + p2);
    if (idx2 < CAPB)
      __builtin_nontemporal_store(s - b2 * BSZ, bins + (size_t)b2 * CAPB + idx2);
  }
}

// ---------------- pass B: per-bucket CSR build + degree/isq, all in LDS ----------------

__global__ __launch_bounds__(256) void binB_kernel(const unsigned* __restrict__ bind,
    const int* __restrict__ bins, const int* __restrict__ gcd, const int* __restrict__ gcs,
    int* __restrict__ cnt, float* __restrict__ isq, int* __restrict__ col) {
  __shared__ int ldc[BSZ], ldeg[BSZ];
  __shared__ int ldcol[BSZ * CAP];   // 38.4 KB
  int b = blockIdx.x;
  for (int i = threadIdx.x; i < BSZ; i += 256) { ldc[i] = 0; ldeg[i] = 0; }
  for (int i = threadIdx.x; i < BSZ * CAP; i += 256) ldcol[i] = 0;
  __syncthreads();
  int nd = min(gcd[b], CAPB);
  int ns = min(gcs[b], CAPB);
  const unsigned* pd = bind + (size_t)b * CAPB;
  const int* ps = bins + (size_t)b * CAPB;
  for (int i = threadIdx.x; i < ns; i += 256)
    atomicAdd(&ldeg[__builtin_nontemporal_load(ps + i)], 1);
  for (int i = threadIdx.x; i < nd; i += 256) {
    unsigned v = __builtin_nontemporal_load(pd + i);
    int dl = (int)(v & 255u);
    int s  = (int)(v >> 8);
    int p = atomicAdd(&ldc[dl], 1);
    if (p < CAP) ldcol[dl * CAP + p] = s;
  }
  __syncthreads();
  int base = b * BSZ;
  for (int i = threadIdx.x; i < BSZ; i += 256) {
    cnt[base + i] = ldc[i];
    int dg = ldeg[i];
    isq[base + i] = dg > 0 ? rsqrtf((float)dg) : 0.0f;
  }
  for (int i = threadIdx.x * 4; i < BSZ * CAP; i += 1024)
    __builtin_nontemporal_store(*(const i32x4*)(ldcol + i),
                                (i32x4*)(col + (size_t)base * CAP + i));
}

// ---------------- fp32 -> bf16 row cast (x snapshot) ----------------

__global__ __launch_bounds__(256) void cast_kernel(const float* __restrict__ in,
                                                   __bf16* __restrict__ outb) {
  size_t base = ((size_t)blockIdx.x * 256 + threadIdx.x) * 8;
  if (base >= (size_t)NN * DD) return;
  f32x4 a0 = __builtin_nontemporal_load((const f32x4*)(in + base));
  f32x4 a1 = __builtin_nontemporal_load((const f32x4*)(in + base + 4));
  bf16x8 ob;
  #pragma unroll
  for (int r = 0; r < 4; ++r) { ob[r] = (__bf16)a0[r]; ob[4 + r] = (__bf16)a1[r]; }
  *(bf16x8*)(outb + base) = ob;   // cached: prop1 gathers xb next
}

// ---------------- propagation: 8-lane group per node, 8 nodes/wave ----------------
// All streaming traffic (col, prev, output) is non-temporal so L2 holds vin rows.

__global__ __launch_bounds__(256) void prop_kernel(const __bf16* __restrict__ vin,
    const __bf16* __restrict__ tprevb, __bf16* __restrict__ voutb,
    const int* __restrict__ cnt, const int* __restrict__ col,
    const float* __restrict__ isq, int mode) {
  int wid = (int)((blockIdx.x * 256u + threadIdx.x) >> 6);
  int lane = threadIdx.x & 63;
  int g = lane >> 3;          // group 0..7 -> node
  int f = lane & 7;           // 8-feature slice
  int node = wid * 8 + g;     // grid sized so node < NN always
  int len = cnt[node]; len = len > CAP ? CAP : len;
  const int* cp = col + (size_t)node * CAP;
  size_t o = (size_t)node * DD + f * 8;

  bf16x8 pv = {};
  if (mode) pv = __builtin_nontemporal_load((const bf16x8*)(tprevb + o));
  float wd = -isq[node];

  float acc[8] = {0, 0, 0, 0, 0, 0, 0, 0};
  int j = 0;
  for (; j + 7 < len; j += 8) {
    i32x4 ca = __builtin_nontemporal_load((const i32x4*)(cp + j));
    i32x4 cb2 = __builtin_nontemporal_load((const i32x4*)(cp + j + 4));
    const int cc[8] = {ca[0], ca[1], ca[2], ca[3], cb2[0], cb2[1], cb2[2], cb2[3]};
    float w[8];
    bf16x8 v[8];
    #pragma unroll
    for (int u = 0; u < 8; ++u) {
      w[u] = isq[cc[u]];
      v[u] = *(const bf16x8*)(vin + (size_t)cc[u] * DD + f * 8);
    }
    #pragma unroll
    for (int u = 0; u < 8; ++u)
      #pragma unroll
      for (int r = 0; r < 8; ++r) acc[r] = fmaf(w[u], (float)v[u][r], acc[r]);
  }
  for (; j + 1 < len; j += 2) {
    int c0 = cp[j], c1 = cp[j + 1];
    float w0 = isq[c0], w1 = isq[c1];
    bf16x8 v0 = *(const bf16x8*)(vin + (size_t)c0 * DD + f * 8);
    bf16x8 v1 = *(const bf16x8*)(vin + (size_t)c1 * DD + f * 8);
    #pragma unroll
    for (int r = 0; r < 8; ++r) acc[r] = fmaf(w0, (float)v0[r], acc[r]);
    #pragma unroll
    for (int r = 0; r < 8; ++r) acc[r] = fmaf(w1, (float)v1[r], acc[r]);
  }
  if (j < len) {
    int c0 = cp[j]; float w0 = isq[c0];
    bf16x8 v0 = *(const bf16x8*)(vin + (size_t)c0 * DD + f * 8);
    #pragma unroll
    for (int r = 0; r < 8; ++r) acc[r] = fmaf(w0, (float)v0[r], acc[r]);
  }

  bf16x8 ob;
  if (mode == 0) {
    #pragma unroll
    for (int r = 0; r < 8; ++r) ob[r] = (__bf16)(wd * acc[r]);
  } else {
    #pragma unroll
    for (int r = 0; r < 8; ++r) ob[r] = (__bf16)(2.0f * (wd * acc[r]) - (float)pv[r]);
  }
  __builtin_nontemporal_store(ob, (bf16x8*)(voutb + o));
}

// ---------------- weight repack into MFMA B-fragment order (bf16) ----------------
// wf[(((p*2+s)*4+t)*64 + lane)*8 + j] = W_p[s*32+(lane>>4)*8+j][t*16+(lane&15)]

__global__ void prep_kernel(const float* __restrict__ cw, const float* __restrict__ w1,
    const float* __restrict__ w2, const float* __restrict__ w3, const float* __restrict__ w4,
    __bf16* __restrict__ wf) {
  int tid = blockIdx.x * 256 + threadIdx.x;   // 9*512 = 4608 total
  if (tid >= 9 * 512) return;
  int p = tid >> 9, rem = tid & 511;
  int s = rem >> 8, t = (rem >> 6) & 3, l = rem & 63;
  const float* W = (p < 5) ? (cw + p * 4096)
                           : (p == 5 ? w1 : p == 6 ? w2 : p == 7 ? w3 : w4);
  int kb = s * 32 + (l >> 4) * 8, cc = t * 16 + (l & 15);
  for (int j = 0; j < 8; ++j)
    wf[(size_t)tid * 8 + j] = (__bf16)W[(kb + j) * 64 + cc];
}

// ---------------- fused dense: h = sum_k txk@Wk + cb; MLP(relu x3); w4+b4; LN ----------------
// tx rows are read exactly once -> non-temporal; out store non-temporal.

__global__ __launch_bounds__(256) void dense_kernel(
    const __bf16* __restrict__ tx0, const __bf16* __restrict__ tx1, const __bf16* __restrict__ tx2,
    const __bf16* __restrict__ tx3, const __bf16* __restrict__ tx4,
    const __bf16* __restrict__ wf,
    const float* __restrict__ cb, const float* __restrict__ b1, const float* __restrict__ b2,
    const float* __restrict__ b3, const float* __restrict__ b4,
    const float* __restrict__ lng, const float* __restrict__ lnb,
    float* __restrict__ out) {
  __shared__ __bf16 stage[4][4][16 * 72];
  int wave = threadIdx.x >> 6, lane = threadIdx.x & 63;
  int l15 = lane & 15, lq = lane >> 4;
  const __bf16* srcs[5] = {tx0, tx1, tx2, tx3, tx4};
  const float* bias[4] = {b1, b2, b3, b4};

  int tile0 = blockIdx.x * 16 + wave * 4;

  f32x4 acc[4][4];
  float cbv[4];
  #pragma unroll
  for (int t = 0; t < 4; ++t) cbv[t] = cb[t * 16 + l15];
  #pragma unroll
  for (int tile = 0; tile < 4; ++tile)
    #pragma unroll
    for (int t = 0; t < 4; ++t)
      acc[tile][t] = (f32x4){cbv[t], cbv[t], cbv[t], cbv[t]};

  // ---- Phase A: sum over 5 Chebyshev terms ----
  #pragma unroll
  for (int k = 0; k < 5; ++k) {
    const __bf16* src = srcs[k];
    bf16x8 bfr[2][4];
    #pragma unroll
    for (int s = 0; s < 2; ++s)
      #pragma unroll
      for (int t = 0; t < 4; ++t)
        bfr[s][t] = *(const bf16x8*)(wf + ((size_t)((k * 2 + s) * 4 + t) * 64 + lane) * 8);
    #pragma unroll
    for (int tile = 0; tile < 4; ++tile) {
      int gt = tile0 + tile;
      if (gt * 16 >= NN) continue;
      const __bf16* rowp = src + (size_t)(gt * 16 + l15) * DD + lq * 8;
      #pragma unroll
      for (int s = 0; s < 2; ++s) {
        bf16x8 af = __builtin_nontemporal_load((const bf16x8*)(rowp + s * 32));
        #pragma unroll
        for (int t = 0; t < 4; ++t)
          acc[tile][t] = __builtin_amdgcn_mfma_f32_16x16x32_bf16(af, bfr[s][t], acc[tile][t], 0, 0, 0);
      }
    }
  }

  // stage h (bf16)
  #pragma unroll
  for (int tile = 0; tile < 4; ++tile)
    #pragma unroll
    for (int t = 0; t < 4; ++t)
      #pragma unroll
      for (int r = 0; r < 4; ++r)
        stage[wave][tile][(lq * 4 + r) * 72 + t * 16 + l15] = (__bf16)acc[tile][t][r];

  // ---- MLP phases p=5..8 ----
  #pragma unroll
  for (int p = 5; p <= 8; ++p) {
    bf16x8 bfr[2][4];
    #pragma unroll
    for (int s = 0; s < 2; ++s)
      #pragma unroll
      for (int t = 0; t < 4; ++t)
        bfr[s][t] = *(const bf16x8*)(wf + ((size_t)((p * 2 + s) * 4 + t) * 64 + lane) * 8);
    float bv[4];
    #pragma unroll
    for (int t = 0; t < 4; ++t) bv[t] = bias[p - 5][t * 16 + l15];
    #pragma unroll
    for (int tile = 0; tile < 4; ++tile) {
      int gt = tile0 + tile;
      if (gt * 16 >= NN) continue;
      f32x4 a2[4];
      #pragma unroll
      for (int t = 0; t < 4; ++t) a2[t] = (f32x4){bv[t], bv[t], bv[t], bv[t]};
      #pragma unroll
      for (int s = 0; s < 2; ++s) {
        bf16x8 af = *(const bf16x8*)&stage[wave][tile][l15 * 72 + s * 32 + lq * 8];
        #pragma unroll
        for (int t = 0; t < 4; ++t)
          a2[t] = __builtin_amdgcn_mfma_f32_16x16x32_bf16(af, bfr[s][t], a2[t], 0, 0, 0);
      }
      if (p < 8) {
        #pragma unroll
        for (int t = 0; t < 4; ++t)
          #pragma unroll
          for (int r = 0; r < 4; ++r) {
            float v = a2[t][r]; v = v > 0.f ? v : 0.f;
            stage[wave][tile][(lq * 4 + r) * 72 + t * 16 + l15] = (__bf16)v;
          }
      } else {
        float sum[4] = {0, 0, 0, 0}, sq[4] = {0, 0, 0, 0};
        #pragma unroll
        for (int t = 0; t < 4; ++t)
          #pragma unroll
          for (int r = 0; r < 4; ++r) { float v = a2[t][r]; sum[r] += v; sq[r] += v * v; }
        #pragma unroll
        for (int m = 1; m < 16; m <<= 1) {
          #pragma unroll
          for (int r = 0; r < 4; ++r) {
            sum[r] += __shfl_xor(sum[r], m, 64);
            sq[r]  += __shfl_xor(sq[r], m, 64);
          }
        }
        float gv[4], bvv[4];
        #pragma unroll
        for (int t = 0; t < 4; ++t) { gv[t] = lng[t * 16 + l15]; bvv[t] = lnb[t * 16 + l15]; }
        #pragma unroll
        for (int r = 0; r < 4; ++r) {
          float mu = sum[r] * (1.0f / 64.0f);
          float var = sq[r] * (1.0f / 64.0f) - mu * mu;
          float rstd = rsqrtf(var + 1e-5f);
          int row = gt * 16 + lq * 4 + r;
          #pragma unroll
          for (int t = 0; t < 4; ++t) {
            float v = (a2[t][r] - mu) * rstd * gv[t] + bvv[t];
            __builtin_nontemporal_store(v, out + (size_t)row * DD + t * 16 + l15);
          }
        }
      }
    }
  }
}

// ---------------- launch ----------------

extern "C" void kernel_launch(void* const* d_in, const int* in_sizes, int n_in,
                              void* d_out, int out_size, void* d_ws, size_t ws_size,
                              hipStream_t stream) {
  const float* x   = (const float*)d_in[0];
  const int*   ei  = (const int*)d_in[1];
  const float* cw  = (const float*)d_in[2];
  const float* cb  = (const float*)d_in[3];
  const float* w1  = (const float*)d_in[4];
  const float* b1  = (const float*)d_in[5];
  const float* w2  = (const float*)d_in[6];
  const float* b2  = (const float*)d_in[7];
  const float* w3  = (const float*)d_in[8];
  const float* b3  = (const float*)d_in[9];
  const float* w4  = (const float*)d_in[10];
  const float* b4  = (const float*)d_in[11];
  const float* lng = (const float*)d_in[12];
  const float* lnb = (const float*)d_in[13];
  float* out = (float*)d_out;

  char* wp = (char*)d_ws;
  auto alloc = [&](size_t b) { char* p = wp; wp += (b + 255) & ~(size_t)255; return (void*)p; };
  int*    gcd = (int*)alloc((size_t)NB * 4);
  int*    gcs = (int*)alloc((size_t)NB * 4);
  int*    cnt = (int*)alloc((size_t)NN * 4);
  float*  isq = (float*)alloc((size_t)NN * 4);
  int*    col = (int*)alloc((size_t)NN * CAP * 4);
  __bf16* xb  = (__bf16*)alloc((size_t)NN * DD * 2);
  __bf16* t1b = (__bf16*)alloc((size_t)NN * DD * 2);
  __bf16* t2b = (__bf16*)alloc((size_t)NN * DD * 2);
  __bf16* t3b = (__bf16*)alloc((size_t)NN * DD * 2);
  __bf16* t4b = (__bf16*)alloc((size_t)NN * DD * 2);
  __bf16* wf  = (__bf16*)alloc((size_t)9 * 4096 * 2);
  (void)ws_size; (void)in_sizes; (void)n_in; (void)out_size;

  // binned streams overlay t3b/t4b (consumed by binB before prop3/prop4 write them)
  unsigned* bind = (unsigned*)t3b;   // NB*CAPB*4 = 8.45MB <= 12.8MB
  int*      bins = (int*)t4b;

  hipMemsetAsync(gcd, 0, (size_t)NB * 4, stream);
  hipMemsetAsync(gcs, 0, (size_t)NB * 4, stream);

  binA_kernel<<<NE / EPB, ABD, 0, stream>>>(ei, gcd, gcs, bind, bins);
  binB_kernel<<<NB, 256, 0, stream>>>(bind, bins, gcd, gcs, cnt, isq, col);
  cast_kernel<<<(NN * DD / 8 + 255) / 256, 256, 0, stream>>>(x, xb);
  prep_kernel<<<18, 256, 0, stream>>>(cw, w1, w2, w3, w4, wf);

  // 8 nodes per wave: 12500 waves = 3125 blocks exactly; all-bf16 state
  prop_kernel<<<NN / 32, 256, 0, stream>>>(xb,  xb,  t1b, cnt, col, isq, 0);
  prop_kernel<<<NN / 32, 256, 0, stream>>>(t1b, xb,  t2b, cnt, col, isq, 1);
  prop_kernel<<<NN / 32, 256, 0, stream>>>(t2b, t1b, t3b, cnt, col, isq, 1);
  prop_kernel<<<NN / 32, 256, 0, stream>>>(t3b, t2b, t4b, cnt, col, isq, 1);

  dense_kernel<<<(NN + 255) / 256, 256, 0, stream>>>(xb, t1b, t2b, t3b, t4b, wf,
                                                     cb, b1, b2, b3, b4, lng, lnb, out);
}

// Round 12
// 237.313 us; speedup vs baseline: 1.3628x; 1.3628x over previous
//
#include <hip/hip_runtime.h>
#include <hip/hip_bf16.h>

#define NN 100000
#define NE 1600000
#define DD 64
#define CAP 48      // max in-degree slots per node
#define NB 500      // buckets
#define BSZ 200     // nodes per bucket (NB*BSZ == NN)
#define CAPB 4224   // edge capacity per bucket (mean 3200, +18 sigma)
#define EPB 6400    // edges per block in pass A (250 blocks, 1024 threads)
#define ABD 1024    // binA block dim
#define PCH 1024    // nodes per block in perm build

typedef __bf16 bf16x8 __attribute__((ext_vector_type(8)));
typedef float f32x4 __attribute__((ext_vector_type(4)));

// ---------------- pass A: bin edges by dst-bucket (and srcs by src-bucket) ----------------

__global__ __launch_bounds__(ABD) void binA_kernel(const int* __restrict__ ei,
    int* __restrict__ gcd, int* __restrict__ gcs,
    unsigned* __restrict__ bind, int* __restrict__ bins) {
  __shared__ int hd[NB], hs[NB], bd[NB], bs[NB];
  int e0 = blockIdx.x * EPB;
  for (int i = threadIdx.x; i < NB; i += ABD) { hd[i] = 0; hs[i] = 0; }
  __syncthreads();
  for (int i = threadIdx.x; i < EPB; i += ABD) {
    int e = e0 + i;
    int s = ei[e], d = ei[NE + e];
    if (s != d) { atomicAdd(&hs[s / BSZ], 1); atomicAdd(&hd[d / BSZ], 1); }
  }
  __syncthreads();
  for (int i = threadIdx.x; i < NB; i += ABD) {
    bd[i] = atomicAdd(&gcd[i], hd[i]);
    bs[i] = atomicAdd(&gcs[i], hs[i]);
  }
  __syncthreads();
  for (int i = threadIdx.x; i < NB; i += ABD) { hd[i] = 0; hs[i] = 0; }
  __syncthreads();
  for (int i = threadIdx.x; i < EPB; i += ABD) {
    int e = e0 + i;
    int s = ei[e], d = ei[NE + e];
    if (s == d) continue;
    int b = d / BSZ;
    int p = atomicAdd(&hd[b], 1);
    unsigned idx = (unsigned)(bd[b] + p);
    if (idx < CAPB) bind[(size_t)b * CAPB + idx] = ((unsigned)s << 8) | (unsigned)(d - b * BSZ);
    int b2 = s / BSZ;
    int p2 = atomicAdd(&hs[b2], 1);
    unsigned idx2 = (unsigned)(bs[b2] + p2);
    if (idx2 < CAPB) bins[(size_t)b2 * CAPB + idx2] = s - b2 * BSZ;
  }
}

// ---------------- pass B: per-bucket CSR build + degree/isq, all in LDS ----------------

__global__ __launch_bounds__(256) void binB_kernel(const unsigned* __restrict__ bind,
    const int* __restrict__ bins, const int* __restrict__ gcd, const int* __restrict__ gcs,
    int* __restrict__ cnt, float* __restrict__ isq, int* __restrict__ col) {
  __shared__ int ldc[BSZ], ldeg[BSZ];
  __shared__ int ldcol[BSZ * CAP];   // 38.4 KB
  int b = blockIdx.x;
  for (int i = threadIdx.x; i < BSZ; i += 256) { ldc[i] = 0; ldeg[i] = 0; }
  for (int i = threadIdx.x; i < BSZ * CAP; i += 256) ldcol[i] = 0;
  __syncthreads();
  int nd = min(gcd[b], CAPB);
  int ns = min(gcs[b], CAPB);
  const unsigned* pd = bind + (size_t)b * CAPB;
  const int* ps = bins + (size_t)b * CAPB;
  for (int i = threadIdx.x; i < ns; i += 256) atomicAdd(&ldeg[ps[i]], 1);
  for (int i = threadIdx.x; i < nd; i += 256) {
    unsigned v = pd[i];
    int dl = (int)(v & 255u);
    int s  = (int)(v >> 8);
    int p = atomicAdd(&ldc[dl], 1);
    if (p < CAP) ldcol[dl * CAP + p] = s;
  }
  __syncthreads();
  int base = b * BSZ;
  for (int i = threadIdx.x; i < BSZ; i += 256) {
    cnt[base + i] = ldc[i];
    int dg = ldeg[i];
    isq[base + i] = dg > 0 ? rsqrtf((float)dg) : 0.0f;
  }
  for (int i = threadIdx.x * 4; i < BSZ * CAP; i += 1024)
    *(int4*)(col + (size_t)base * CAP + i) = *(const int4*)(ldcol + i);
}

// ---------------- degree-sorted permutation (counting sort, LDS-privatized) ----------------

__global__ __launch_bounds__(256) void histo_kernel(const int* __restrict__ cnt,
                                                    int* __restrict__ hbin) {
  __shared__ int lh[CAP + 1];
  for (int i = threadIdx.x; i <= CAP; i += 256) lh[i] = 0;
  __syncthreads();
  int n0 = blockIdx.x * PCH;
  for (int i = threadIdx.x; i < PCH; i += 256) {
    int g = n0 + i;
    if (g < NN) { int l = cnt[g]; l = l > CAP ? CAP : l; atomicAdd(&lh[l], 1); }
  }
  __syncthreads();
  for (int i = threadIdx.x; i <= CAP; i += 256)
    if (lh[i]) atomicAdd(&hbin[i], lh[i]);
}

__global__ void prefix_kernel(int* __restrict__ hbin) {
  if (threadIdx.x == 0) {
    int run = 0;
    for (int i = 0; i <= CAP; ++i) { int c = hbin[i]; hbin[i] = run; run += c; }
  }
}

__global__ __launch_bounds__(256) void scatperm_kernel(const int* __restrict__ cnt,
    int* __restrict__ hbin, int* __restrict__ perm) {
  __shared__ int lh[CAP + 1], lb[CAP + 1];
  for (int i = threadIdx.x; i <= CAP; i += 256) lh[i] = 0;
  __syncthreads();
  int n0 = blockIdx.x * PCH;
  for (int i = threadIdx.x; i < PCH; i += 256) {
    int g = n0 + i;
    if (g < NN) { int l = cnt[g]; l = l > CAP ? CAP : l; atomicAdd(&lh[l], 1); }
  }
  __syncthreads();
  for (int i = threadIdx.x; i <= CAP; i += 256)
    lb[i] = lh[i] ? atomicAdd(&hbin[i], lh[i]) : 0;
  __syncthreads();
  for (int i = threadIdx.x; i <= CAP; i += 256) lh[i] = 0;
  __syncthreads();
  for (int i = threadIdx.x; i < PCH; i += 256) {
    int g = n0 + i;
    if (g < NN) {
      int l = cnt[g]; l = l > CAP ? CAP : l;
      int p = atomicAdd(&lh[l], 1);
      perm[lb[l] + p] = g;
    }
  }
}

// ---------------- fp32 -> bf16 row cast (x snapshot) ----------------

__global__ __launch_bounds__(256) void cast_kernel(const float* __restrict__ in,
                                                   __bf16* __restrict__ outb) {
  size_t base = ((size_t)blockIdx.x * 256 + threadIdx.x) * 8;
  if (base >= (size_t)NN * DD) return;
  f32x4 a0 = *(const f32x4*)(in + base);
  f32x4 a1 = *(const f32x4*)(in + base + 4);
  bf16x8 ob;
  #pragma unroll
  for (int r = 0; r < 4; ++r) { ob[r] = (__bf16)a0[r]; ob[4 + r] = (__bf16)a1[r]; }
  *(bf16x8*)(outb + base) = ob;
}

// ---------------- propagation: 8-lane group per node, degree-sorted assignment ----------------
// Wave's 8 nodes come from perm (sorted by degree) -> equal loop lengths, no
// exec-masked dead iterations.  All-bf16 state.

__global__ __launch_bounds__(256) void prop_kernel(const __bf16* __restrict__ vin,
    const __bf16* __restrict__ tprevb, __bf16* __restrict__ voutb,
    const int* __restrict__ cnt, const int* __restrict__ col,
    const float* __restrict__ isq, const int* __restrict__ perm, int mode) {
  int wid = (int)((blockIdx.x * 256u + threadIdx.x) >> 6);
  int lane = threadIdx.x & 63;
  int g = lane >> 3;          // group 0..7 -> node slot
  int f = lane & 7;           // 8-feature slice
  int node = perm[wid * 8 + g];
  int len = cnt[node]; len = len > CAP ? CAP : len;
  const int* cp = col + (size_t)node * CAP;
  size_t o = (size_t)node * DD + f * 8;

  bf16x8 pv = {};
  if (mode) pv = *(const bf16x8*)(tprevb + o);
  float wd = -isq[node];

  float acc[8] = {0, 0, 0, 0, 0, 0, 0, 0};
  int j = 0;
  for (; j + 7 < len; j += 8) {
    int4 ca = *(const int4*)(cp + j);
    int4 cb2 = *(const int4*)(cp + j + 4);
    const int cc[8] = {ca.x, ca.y, ca.z, ca.w, cb2.x, cb2.y, cb2.z, cb2.w};
    float w[8];
    bf16x8 v[8];
    #pragma unroll
    for (int u = 0; u < 8; ++u) {
      w[u] = isq[cc[u]];
      v[u] = *(const bf16x8*)(vin + (size_t)cc[u] * DD + f * 8);
    }
    #pragma unroll
    for (int u = 0; u < 8; ++u)
      #pragma unroll
      for (int r = 0; r < 8; ++r) acc[r] = fmaf(w[u], (float)v[u][r], acc[r]);
  }
  for (; j + 1 < len; j += 2) {
    int c0 = cp[j], c1 = cp[j + 1];
    float w0 = isq[c0], w1 = isq[c1];
    bf16x8 v0 = *(const bf16x8*)(vin + (size_t)c0 * DD + f * 8);
    bf16x8 v1 = *(const bf16x8*)(vin + (size_t)c1 * DD + f * 8);
    #pragma unroll
    for (int r = 0; r < 8; ++r) acc[r] = fmaf(w0, (float)v0[r], acc[r]);
    #pragma unroll
    for (int r = 0; r < 8; ++r) acc[r] = fmaf(w1, (float)v1[r], acc[r]);
  }
  if (j < len) {
    int c0 = cp[j]; float w0 = isq[c0];
    bf16x8 v0 = *(const bf16x8*)(vin + (size_t)c0 * DD + f * 8);
    #pragma unroll
    for (int r = 0; r < 8; ++r) acc[r] = fmaf(w0, (float)v0[r], acc[r]);
  }

  bf16x8 ob;
  if (mode == 0) {
    #pragma unroll
    for (int r = 0; r < 8; ++r) ob[r] = (__bf16)(wd * acc[r]);
  } else {
    #pragma unroll
    for (int r = 0; r < 8; ++r) ob[r] = (__bf16)(2.0f * (wd * acc[r]) - (float)pv[r]);
  }
  *(bf16x8*)(voutb + o) = ob;
}

// ---------------- weight repack into MFMA B-fragment order (bf16) ----------------
// wf[(((p*2+s)*4+t)*64 + lane)*8 + j] = W_p[s*32+(lane>>4)*8+j][t*16+(lane&15)]

__global__ void prep_kernel(const float* __restrict__ cw, const float* __restrict__ w1,
    const float* __restrict__ w2, const float* __restrict__ w3, const float* __restrict__ w4,
    __bf16* __restrict__ wf) {
  int tid = blockIdx.x * 256 + threadIdx.x;   // 9*512 = 4608 total
  if (tid >= 9 * 512) return;
  int p = tid >> 9, rem = tid & 511;
  int s = rem >> 8, t = (rem >> 6) & 3, l = rem & 63;
  const float* W = (p < 5) ? (cw + p * 4096)
                           : (p == 5 ? w1 : p == 6 ? w2 : p == 7 ? w3 : w4);
  int kb = s * 32 + (l >> 4) * 8, cc = t * 16 + (l & 15);
  for (int j = 0; j < 8; ++j)
    wf[(size_t)tid * 8 + j] = (__bf16)W[(kb + j) * 64 + cc];
}

// ---------------- fused dense: h = sum_k txk@Wk + cb; MLP(relu x3); w4+b4; LN ----------------

__global__ __launch_bounds__(256) void dense_kernel(
    const __bf16* __restrict__ tx0, const __bf16* __restrict__ tx1, const __bf16* __restrict__ tx2,
    const __bf16* __restrict__ tx3, const __bf16* __restrict__ tx4,
    const __bf16* __restrict__ wf,
    const float* __restrict__ cb, const float* __restrict__ b1, const float* __restrict__ b2,
    const float* __restrict__ b3, const float* __restrict__ b4,
    const float* __restrict__ lng, const float* __restrict__ lnb,
    float* __restrict__ out) {
  __shared__ __bf16 stage[4][4][16 * 72];
  int wave = threadIdx.x >> 6, lane = threadIdx.x & 63;
  int l15 = lane & 15, lq = lane >> 4;
  const __bf16* srcs[5] = {tx0, tx1, tx2, tx3, tx4};
  const float* bias[4] = {b1, b2, b3, b4};

  int tile0 = blockIdx.x * 16 + wave * 4;

  f32x4 acc[4][4];
  float cbv[4];
  #pragma unroll
  for (int t = 0; t < 4; ++t) cbv[t] = cb[t * 16 + l15];
  #pragma unroll
  for (int tile = 0; tile < 4; ++tile)
    #pragma unroll
    for (int t = 0; t < 4; ++t)
      acc[tile][t] = (f32x4){cbv[t], cbv[t], cbv[t], cbv[t]};

  // ---- Phase A: sum over 5 Chebyshev terms ----
  #pragma unroll
  for (int k = 0; k < 5; ++k) {
    const __bf16* src = srcs[k];
    bf16x8 bfr[2][4];
    #pragma unroll
    for (int s = 0; s < 2; ++s)
      #pragma unroll
      for (int t = 0; t < 4; ++t)
        bfr[s][t] = *(const bf16x8*)(wf + ((size_t)((k * 2 + s) * 4 + t) * 64 + lane) * 8);
    #pragma unroll
    for (int tile = 0; tile < 4; ++tile) {
      int gt = tile0 + tile;
      if (gt * 16 >= NN) continue;
      const __bf16* rowp = src + (size_t)(gt * 16 + l15) * DD + lq * 8;
      #pragma unroll
      for (int s = 0; s < 2; ++s) {
        bf16x8 af = *(const bf16x8*)(rowp + s * 32);
        #pragma unroll
        for (int t = 0; t < 4; ++t)
          acc[tile][t] = __builtin_amdgcn_mfma_f32_16x16x32_bf16(af, bfr[s][t], acc[tile][t], 0, 0, 0);
      }
    }
  }

  // stage h (bf16)
  #pragma unroll
  for (int tile = 0; tile < 4; ++tile)
    #pragma unroll
    for (int t = 0; t < 4; ++t)
      #pragma unroll
      for (int r = 0; r < 4; ++r)
        stage[wave][tile][(lq * 4 + r) * 72 + t * 16 + l15] = (__bf16)acc[tile][t][r];

  // ---- MLP phases p=5..8 ----
  #pragma unroll
  for (int p = 5; p <= 8; ++p) {
    bf16x8 bfr[2][4];
    #pragma unroll
    for (int s = 0; s < 2; ++s)
      #pragma unroll
      for (int t = 0; t < 4; ++t)
        bfr[s][t] = *(const bf16x8*)(wf + ((size_t)((p * 2 + s) * 4 + t) * 64 + lane) * 8);
    float bv[4];
    #pragma unroll
    for (int t = 0; t < 4; ++t) bv[t] = bias[p - 5][t * 16 + l15];
    #pragma unroll
    for (int tile = 0; tile < 4; ++tile) {
      int gt = tile0 + tile;
      if (gt * 16 >= NN) continue;
      f32x4 a2[4];
      #pragma unroll
      for (int t = 0; t < 4; ++t) a2[t] = (f32x4){bv[t], bv[t], bv[t], bv[t]};
      #pragma unroll
      for (int s = 0; s < 2; ++s) {
        bf16x8 af = *(const bf16x8*)&stage[wave][tile][l15 * 72 + s * 32 + lq * 8];
        #pragma unroll
        for (int t = 0; t < 4; ++t)
          a2[t] = __builtin_amdgcn_mfma_f32_16x16x32_bf16(af, bfr[s][t], a2[t], 0, 0, 0);
      }
      if (p < 8) {
        #pragma unroll
        for (int t = 0; t < 4; ++t)
          #pragma unroll
          for (int r = 0; r < 4; ++r) {
            float v = a2[t][r]; v = v > 0.f ? v : 0.f;
            stage[wave][tile][(lq * 4 + r) * 72 + t * 16 + l15] = (__bf16)v;
          }
      } else {
        float sum[4] = {0, 0, 0, 0}, sq[4] = {0, 0, 0, 0};
        #pragma unroll
        for (int t = 0; t < 4; ++t)
          #pragma unroll
          for (int r = 0; r < 4; ++r) { float v = a2[t][r]; sum[r] += v; sq[r] += v * v; }
        #pragma unroll
        for (int m = 1; m < 16; m <<= 1) {
          #pragma unroll
          for (int r = 0; r < 4; ++r) {
            sum[r] += __shfl_xor(sum[r], m, 64);
            sq[r]  += __shfl_xor(sq[r], m, 64);
          }
        }
        float gv[4], bvv[4];
        #pragma unroll
        for (int t = 0; t < 4; ++t) { gv[t] = lng[t * 16 + l15]; bvv[t] = lnb[t * 16 + l15]; }
        #pragma unroll
        for (int r = 0; r < 4; ++r) {
          float mu = sum[r] * (1.0f / 64.0f);
          float var = sq[r] * (1.0f / 64.0f) - mu * mu;
          float rstd = rsqrtf(var + 1e-5f);
          int row = gt * 16 + lq * 4 + r;
          #pragma unroll
          for (int t = 0; t < 4; ++t) {
            float v = (a2[t][r] - mu) * rstd * gv[t] + bvv[t];
            out[(size_t)row * DD + t * 16 + l15] = v;
          }
        }
      }
    }
  }
}

// ---------------- launch ----------------

extern "C" void kernel_launch(void* const* d_in, const int* in_sizes, int n_in,
                              void* d_out, int out_size, void* d_ws, size_t ws_size,
                              hipStream_t stream) {
  const float* x   = (const float*)d_in[0];
  const int*   ei  = (const int*)d_in[1];
  const float* cw  = (const float*)d_in[2];
  const float* cb  = (const float*)d_in[3];
  const float* w1  = (const float*)d_in[4];
  const float* b1  = (const float*)d_in[5];
  const float* w2  = (const float*)d_in[6];
  const float* b2  = (const float*)d_in[7];
  const float* w3  = (const float*)d_in[8];
  const float* b3  = (const float*)d_in[9];
  const float* w4  = (const float*)d_in[10];
  const float* b4  = (const float*)d_in[11];
  const float* lng = (const float*)d_in[12];
  const float* lnb = (const float*)d_in[13];
  float* out = (float*)d_out;

  char* wp = (char*)d_ws;
  auto alloc = [&](size_t b) { char* p = wp; wp += (b + 255) & ~(size_t)255; return (void*)p; };
  int*    gcd  = (int*)alloc((size_t)NB * 4);
  int*    gcs  = (int*)alloc((size_t)NB * 4);
  int*    hbin = (int*)alloc((size_t)(CAP + 1) * 4);
  int*    cnt  = (int*)alloc((size_t)NN * 4);
  float*  isq  = (float*)alloc((size_t)NN * 4);
  int*    perm = (int*)alloc((size_t)NN * 4);
  int*    col  = (int*)alloc((size_t)NN * CAP * 4);
  __bf16* xb   = (__bf16*)alloc((size_t)NN * DD * 2);
  __bf16* t1b  = (__bf16*)alloc((size_t)NN * DD * 2);
  __bf16* t2b  = (__bf16*)alloc((size_t)NN * DD * 2);
  __bf16* t3b  = (__bf16*)alloc((size_t)NN * DD * 2);
  __bf16* t4b  = (__bf16*)alloc((size_t)NN * DD * 2);
  __bf16* wf   = (__bf16*)alloc((size_t)9 * 4096 * 2);
  (void)ws_size; (void)in_sizes; (void)n_in; (void)out_size;

  // binned streams overlay t3b/t4b (consumed by binB before prop3/prop4 write them)
  unsigned* bind = (unsigned*)t3b;   // NB*CAPB*4 = 8.45MB <= 12.8MB
  int*      bins = (int*)t4b;

  hipMemsetAsync(gcd, 0, (size_t)NB * 4, stream);
  hipMemsetAsync(gcs, 0, (size_t)NB * 4, stream);
  hipMemsetAsync(hbin, 0, (size_t)(CAP + 1) * 4, stream);

  binA_kernel<<<NE / EPB, ABD, 0, stream>>>(ei, gcd, gcs, bind, bins);
  binB_kernel<<<NB, 256, 0, stream>>>(bind, bins, gcd, gcs, cnt, isq, col);
  histo_kernel<<<(NN + PCH - 1) / PCH, 256, 0, stream>>>(cnt, hbin);
  prefix_kernel<<<1, 64, 0, stream>>>(hbin);
  scatperm_kernel<<<(NN + PCH - 1) / PCH, 256, 0, stream>>>(cnt, hbin, perm);
  cast_kernel<<<(NN * DD / 8 + 255) / 256, 256, 0, stream>>>(x, xb);
  prep_kernel<<<18, 256, 0, stream>>>(cw, w1, w2, w3, w4, wf);

  // 8 nodes per wave via degree-sorted perm: 12500 waves = 3125 blocks
  prop_kernel<<<NN / 32, 256, 0, stream>>>(xb,  xb,  t1b, cnt, col, isq, perm, 0);
  prop_kernel<<<NN / 32, 256, 0, stream>>>(t1b, xb,  t2b, cnt, col, isq, perm, 1);
  prop_kernel<<<NN / 32, 256, 0, stream>>>(t2b, t1b, t3b, cnt, col, isq, perm, 1);
  prop_kernel<<<NN / 32, 256, 0, stream>>>(t3b, t2b, t4b, cnt, col, isq, perm, 1);

  dense_kernel<<<(NN + 255) / 256, 256, 0, stream>>>(xb, t1b, t2b, t3b, t4b, wf,
                                                     cb, b1, b2, b3, b4, lng, lnb, out);
}

// Round 13
// 232.796 us; speedup vs baseline: 1.3892x; 1.0194x over previous
//
#include <hip/hip_runtime.h>
#include <hip/hip_bf16.h>

#define NN 100000
#define NE 1600000
#define DD 64
#define CAP 48      // max in-degree slots per node
#define NB 500      // buckets
#define BSZ 200     // nodes per bucket (NB*BSZ == NN)
#define CAPB 4224   // edge capacity per bucket (mean 3200, +18 sigma)
#define EPB 6400    // edges per block in pass A (250 blocks, 1024 threads)
#define ABD 1024    // binA block dim

typedef __bf16 bf16x8 __attribute__((ext_vector_type(8)));
typedef float f32x4 __attribute__((ext_vector_type(4)));

// ---------------- pass A: bin edges by dst-bucket (and srcs by src-bucket) ----------------
// 1024 threads/block for latency hiding; EPB=6400 keeps per-bucket runs ~51B
// (~1 line) so scattered stores coalesce in L2.

__global__ __launch_bounds__(ABD) void binA_kernel(const int* __restrict__ ei,
    int* __restrict__ gcd, int* __restrict__ gcs,
    unsigned* __restrict__ bind, int* __restrict__ bins) {
  __shared__ int hd[NB], hs[NB], bd[NB], bs[NB];
  int e0 = blockIdx.x * EPB;
  for (int i = threadIdx.x; i < NB; i += ABD) { hd[i] = 0; hs[i] = 0; }
  __syncthreads();
  for (int i = threadIdx.x; i < EPB; i += ABD) {
    int e = e0 + i;
    int s = ei[e], d = ei[NE + e];
    if (s != d) { atomicAdd(&hs[s / BSZ], 1); atomicAdd(&hd[d / BSZ], 1); }
  }
  __syncthreads();
  for (int i = threadIdx.x; i < NB; i += ABD) {
    bd[i] = atomicAdd(&gcd[i], hd[i]);
    bs[i] = atomicAdd(&gcs[i], hs[i]);
  }
  __syncthreads();
  for (int i = threadIdx.x; i < NB; i += ABD) { hd[i] = 0; hs[i] = 0; }
  __syncthreads();
  for (int i = threadIdx.x; i < EPB; i += ABD) {
    int e = e0 + i;
    int s = ei[e], d = ei[NE + e];
    if (s == d) continue;
    int b = d / BSZ;
    int p = atomicAdd(&hd[b], 1);
    unsigned idx = (unsigned)(bd[b] + p);
    if (idx < CAPB) bind[(size_t)b * CAPB + idx] = ((unsigned)s << 8) | (unsigned)(d - b * BSZ);
    int b2 = s / BSZ;
    int p2 = atomicAdd(&hs[b2], 1);
    unsigned idx2 = (unsigned)(bs[b2] + p2);
    if (idx2 < CAPB) bins[(size_t)b2 * CAPB + idx2] = s - b2 * BSZ;
  }
}

// ---------------- pass B: per-bucket CSR build + degree/isq, all in LDS ----------------

__global__ __launch_bounds__(256) void binB_kernel(const unsigned* __restrict__ bind,
    const int* __restrict__ bins, const int* __restrict__ gcd, const int* __restrict__ gcs,
    int* __restrict__ cnt, float* __restrict__ isq, int* __restrict__ col) {
  __shared__ int ldc[BSZ], ldeg[BSZ];
  __shared__ int ldcol[BSZ * CAP];   // 38.4 KB
  int b = blockIdx.x;
  for (int i = threadIdx.x; i < BSZ; i += 256) { ldc[i] = 0; ldeg[i] = 0; }
  for (int i = threadIdx.x; i < BSZ * CAP; i += 256) ldcol[i] = 0;
  __syncthreads();
  int nd = min(gcd[b], CAPB);
  int ns = min(gcs[b], CAPB);
  const unsigned* pd = bind + (size_t)b * CAPB;
  const int* ps = bins + (size_t)b * CAPB;
  for (int i = threadIdx.x; i < ns; i += 256) atomicAdd(&ldeg[ps[i]], 1);
  for (int i = threadIdx.x; i < nd; i += 256) {
    unsigned v = pd[i];
    int dl = (int)(v & 255u);
    int s  = (int)(v >> 8);
    int p = atomicAdd(&ldc[dl], 1);
    if (p < CAP) ldcol[dl * CAP + p] = s;
  }
  __syncthreads();
  int base = b * BSZ;
  for (int i = threadIdx.x; i < BSZ; i += 256) {
    cnt[base + i] = ldc[i];
    int dg = ldeg[i];
    isq[base + i] = dg > 0 ? rsqrtf((float)dg) : 0.0f;
  }
  for (int i = threadIdx.x * 4; i < BSZ * CAP; i += 1024)
    *(int4*)(col + (size_t)base * CAP + i) = *(const int4*)(ldcol + i);
}

// ---------------- fp32 -> bf16 row cast (x snapshot) ----------------

__global__ __launch_bounds__(256) void cast_kernel(const float* __restrict__ in,
                                                   __bf16* __restrict__ outb) {
  size_t base = ((size_t)blockIdx.x * 256 + threadIdx.x) * 8;
  if (base >= (size_t)NN * DD) return;
  f32x4 a0 = *(const f32x4*)(in + base);
  f32x4 a1 = *(const f32x4*)(in + base + 4);
  bf16x8 ob;
  #pragma unroll
  for (int r = 0; r < 4; ++r) { ob[r] = (__bf16)a0[r]; ob[4 + r] = (__bf16)a1[r]; }
  *(bf16x8*)(outb + base) = ob;
}

// ---------------- propagation: 8-lane group per node, 8 nodes/wave, unroll-8 gathers ----------------
// acc = sum_j isq[c]*vin[c]; res = -isq[n]*acc (mode0) or 2*(-isq[n]*acc) - prevb (mode1).
// Cols read as int4 pairs (coalesced); 8 row-gathers in flight per group.

__global__ __launch_bounds__(256) void prop_kernel(const __bf16* __restrict__ vin,
    const __bf16* __restrict__ tprevb, __bf16* __restrict__ voutb,
    const int* __restrict__ cnt, const int* __restrict__ col,
    const float* __restrict__ isq, int mode) {
  int wid = (int)((blockIdx.x * 256u + threadIdx.x) >> 6);
  int lane = threadIdx.x & 63;
  int g = lane >> 3;          // group 0..7 -> node
  int f = lane & 7;           // 8-feature slice
  int node = wid * 8 + g;     // grid sized so node < NN always
  int len = cnt[node]; len = len > CAP ? CAP : len;
  const int* cp = col + (size_t)node * CAP;
  size_t o = (size_t)node * DD + f * 8;

  bf16x8 pv = {};
  if (mode) pv = *(const bf16x8*)(tprevb + o);
  float wd = -isq[node];

  float acc[8] = {0, 0, 0, 0, 0, 0, 0, 0};
  int j = 0;
  for (; j + 7 < len; j += 8) {
    int4 ca = *(const int4*)(cp + j);
    int4 cb2 = *(const int4*)(cp + j + 4);
    const int cc[8] = {ca.x, ca.y, ca.z, ca.w, cb2.x, cb2.y, cb2.z, cb2.w};
    float w[8];
    bf16x8 v[8];
    #pragma unroll
    for (int u = 0; u < 8; ++u) {
      w[u] = isq[cc[u]];
      v[u] = *(const bf16x8*)(vin + (size_t)cc[u] * DD + f * 8);
    }
    #pragma unroll
    for (int u = 0; u < 8; ++u)
      #pragma unroll
      for (int r = 0; r < 8; ++r) acc[r] = fmaf(w[u], (float)v[u][r], acc[r]);
  }
  for (; j + 1 < len; j += 2) {
    int c0 = cp[j], c1 = cp[j + 1];
    float w0 = isq[c0], w1 = isq[c1];
    bf16x8 v0 = *(const bf16x8*)(vin + (size_t)c0 * DD + f * 8);
    bf16x8 v1 = *(const bf16x8*)(vin + (size_t)c1 * DD + f * 8);
    #pragma unroll
    for (int r = 0; r < 8; ++r) acc[r] = fmaf(w0, (float)v0[r], acc[r]);
    #pragma unroll
    for (int r = 0; r < 8; ++r) acc[r] = fmaf(w1, (float)v1[r], acc[r]);
  }
  if (j < len) {
    int c0 = cp[j]; float w0 = isq[c0];
    bf16x8 v0 = *(const bf16x8*)(vin + (size_t)c0 * DD + f * 8);
    #pragma unroll
    for (int r = 0; r < 8; ++r) acc[r] = fmaf(w0, (float)v0[r], acc[r]);
  }

  bf16x8 ob;
  if (mode == 0) {
    #pragma unroll
    for (int r = 0; r < 8; ++r) ob[r] = (__bf16)(wd * acc[r]);
  } else {
    #pragma unroll
    for (int r = 0; r < 8; ++r) ob[r] = (__bf16)(2.0f * (wd * acc[r]) - (float)pv[r]);
  }
  *(bf16x8*)(voutb + o) = ob;
}

// ---------------- weight repack into MFMA B-fragment order (bf16) ----------------
// wf[(((p*2+s)*4+t)*64 + lane)*8 + j] = W_p[s*32+(lane>>4)*8+j][t*16+(lane&15)]

__global__ void prep_kernel(const float* __restrict__ cw, const float* __restrict__ w1,
    const float* __restrict__ w2, const float* __restrict__ w3, const float* __restrict__ w4,
    __bf16* __restrict__ wf) {
  int tid = blockIdx.x * 256 + threadIdx.x;   // 9*512 = 4608 total
  if (tid >= 9 * 512) return;
  int p = tid >> 9, rem = tid & 511;
  int s = rem >> 8, t = (rem >> 6) & 3, l = rem & 63;
  const float* W = (p < 5) ? (cw + p * 4096)
                           : (p == 5 ? w1 : p == 6 ? w2 : p == 7 ? w3 : w4);
  int kb = s * 32 + (l >> 4) * 8, cc = t * 16 + (l & 15);
  for (int j = 0; j < 8; ++j)
    wf[(size_t)tid * 8 + j] = (__bf16)W[(kb + j) * 64 + cc];
}

// ---------------- fused dense: h = sum_k txk@Wk + cb; MLP(relu x3); w4+b4; LN ----------------

__global__ __launch_bounds__(256) void dense_kernel(
    const __bf16* __restrict__ tx0, const __bf16* __restrict__ tx1, const __bf16* __restrict__ tx2,
    const __bf16* __restrict__ tx3, const __bf16* __restrict__ tx4,
    const __bf16* __restrict__ wf,
    const float* __restrict__ cb, const float* __restrict__ b1, const float* __restrict__ b2,
    const float* __restrict__ b3, const float* __restrict__ b4,
    const float* __restrict__ lng, const float* __restrict__ lnb,
    float* __restrict__ out) {
  __shared__ __bf16 stage[4][4][16 * 72];
  int wave = threadIdx.x >> 6, lane = threadIdx.x & 63;
  int l15 = lane & 15, lq = lane >> 4;
  const __bf16* srcs[5] = {tx0, tx1, tx2, tx3, tx4};
  const float* bias[4] = {b1, b2, b3, b4};

  int tile0 = blockIdx.x * 16 + wave * 4;

  f32x4 acc[4][4];
  float cbv[4];
  #pragma unroll
  for (int t = 0; t < 4; ++t) cbv[t] = cb[t * 16 + l15];
  #pragma unroll
  for (int tile = 0; tile < 4; ++tile)
    #pragma unroll
    for (int t = 0; t < 4; ++t)
      acc[tile][t] = (f32x4){cbv[t], cbv[t], cbv[t], cbv[t]};

  // ---- Phase A: sum over 5 Chebyshev terms ----
  #pragma unroll
  for (int k = 0; k < 5; ++k) {
    const __bf16* src = srcs[k];
    bf16x8 bfr[2][4];
    #pragma unroll
    for (int s = 0; s < 2; ++s)
      #pragma unroll
      for (int t = 0; t < 4; ++t)
        bfr[s][t] = *(const bf16x8*)(wf + ((size_t)((k * 2 + s) * 4 + t) * 64 + lane) * 8);
    #pragma unroll
    for (int tile = 0; tile < 4; ++tile) {
      int gt = tile0 + tile;
      if (gt * 16 >= NN) continue;
      const __bf16* rowp = src + (size_t)(gt * 16 + l15) * DD + lq * 8;
      #pragma unroll
      for (int s = 0; s < 2; ++s) {
        bf16x8 af = *(const bf16x8*)(rowp + s * 32);
        #pragma unroll
        for (int t = 0; t < 4; ++t)
          acc[tile][t] = __builtin_amdgcn_mfma_f32_16x16x32_bf16(af, bfr[s][t], acc[tile][t], 0, 0, 0);
      }
    }
  }

  // stage h (bf16)
  #pragma unroll
  for (int tile = 0; tile < 4; ++tile)
    #pragma unroll
    for (int t = 0; t < 4; ++t)
      #pragma unroll
      for (int r = 0; r < 4; ++r)
        stage[wave][tile][(lq * 4 + r) * 72 + t * 16 + l15] = (__bf16)acc[tile][t][r];

  // ---- MLP phases p=5..8 ----
  #pragma unroll
  for (int p = 5; p <= 8; ++p) {
    bf16x8 bfr[2][4];
    #pragma unroll
    for (int s = 0; s < 2; ++s)
      #pragma unroll
      for (int t = 0; t < 4; ++t)
        bfr[s][t] = *(const bf16x8*)(wf + ((size_t)((p * 2 + s) * 4 + t) * 64 + lane) * 8);
    float bv[4];
    #pragma unroll
    for (int t = 0; t < 4; ++t) bv[t] = bias[p - 5][t * 16 + l15];
    #pragma unroll
    for (int tile = 0; tile < 4; ++tile) {
      int gt = tile0 + tile;
      if (gt * 16 >= NN) continue;
      f32x4 a2[4];
      #pragma unroll
      for (int t = 0; t < 4; ++t) a2[t] = (f32x4){bv[t], bv[t], bv[t], bv[t]};
      #pragma unroll
      for (int s = 0; s < 2; ++s) {
        bf16x8 af = *(const bf16x8*)&stage[wave][tile][l15 * 72 + s * 32 + lq * 8];
        #pragma unroll
        for (int t = 0; t < 4; ++t)
          a2[t] = __builtin_amdgcn_mfma_f32_16x16x32_bf16(af, bfr[s][t], a2[t], 0, 0, 0);
      }
      if (p < 8) {
        #pragma unroll
        for (int t = 0; t < 4; ++t)
          #pragma unroll
          for (int r = 0; r < 4; ++r) {
            float v = a2[t][r]; v = v > 0.f ? v : 0.f;
            stage[wave][tile][(lq * 4 + r) * 72 + t * 16 + l15] = (__bf16)v;
          }
      } else {
        float sum[4] = {0, 0, 0, 0}, sq[4] = {0, 0, 0, 0};
        #pragma unroll
        for (int t = 0; t < 4; ++t)
          #pragma unroll
          for (int r = 0; r < 4; ++r) { float v = a2[t][r]; sum[r] += v; sq[r] += v * v; }
        #pragma unroll
        for (int m = 1; m < 16; m <<= 1) {
          #pragma unroll
          for (int r = 0; r < 4; ++r) {
            sum[r] += __shfl_xor(sum[r], m, 64);
            sq[r]  += __shfl_xor(sq[r], m, 64);
          }
        }
        float gv[4], bvv[4];
        #pragma unroll
        for (int t = 0; t < 4; ++t) { gv[t] = lng[t * 16 + l15]; bvv[t] = lnb[t * 16 + l15]; }
        #pragma unroll
        for (int r = 0; r < 4; ++r) {
          float mu = sum[r] * (1.0f / 64.0f);
          float var = sq[r] * (1.0f / 64.0f) - mu * mu;
          float rstd = rsqrtf(var + 1e-5f);
          int row = gt * 16 + lq * 4 + r;
          #pragma unroll
          for (int t = 0; t < 4; ++t) {
            float v = (a2[t][r] - mu) * rstd * gv[t] + bvv[t];
            out[(size_t)row * DD + t * 16 + l15] = v;
          }
        }
      }
    }
  }
}

// ---------------- launch ----------------

extern "C" void kernel_launch(void* const* d_in, const int* in_sizes, int n_in,
                              void* d_out, int out_size, void* d_ws, size_t ws_size,
                              hipStream_t stream) {
  const float* x   = (const float*)d_in[0];
  const int*   ei  = (const int*)d_in[1];
  const float* cw  = (const float*)d_in[2];
  const float* cb  = (const float*)d_in[3];
  const float* w1  = (const float*)d_in[4];
  const float* b1  = (const float*)d_in[5];
  const float* w2  = (const float*)d_in[6];
  const float* b2  = (const float*)d_in[7];
  const float* w3  = (const float*)d_in[8];
  const float* b3  = (const float*)d_in[9];
  const float* w4  = (const float*)d_in[10];
  const float* b4  = (const float*)d_in[11];
  const float* lng = (const float*)d_in[12];
  const float* lnb = (const float*)d_in[13];
  float* out = (float*)d_out;

  char* wp = (char*)d_ws;
  auto alloc = [&](size_t b) { char* p = wp; wp += (b + 255) & ~(size_t)255; return (void*)p; };
  int*    gcd = (int*)alloc((size_t)NB * 4);
  int*    gcs = (int*)alloc((size_t)NB * 4);
  int*    cnt = (int*)alloc((size_t)NN * 4);
  float*  isq = (float*)alloc((size_t)NN * 4);
  int*    col = (int*)alloc((size_t)NN * CAP * 4);
  __bf16* xb  = (__bf16*)alloc((size_t)NN * DD * 2);
  __bf16* t1b = (__bf16*)alloc((size_t)NN * DD * 2);
  __bf16* t2b = (__bf16*)alloc((size_t)NN * DD * 2);
  __bf16* t3b = (__bf16*)alloc((size_t)NN * DD * 2);
  __bf16* t4b = (__bf16*)alloc((size_t)NN * DD * 2);
  __bf16* wf  = (__bf16*)alloc((size_t)9 * 4096 * 2);
  (void)ws_size; (void)in_sizes; (void)n_in; (void)out_size;

  // binned streams overlay t3b/t4b (consumed by binB before prop3/prop4 write them)
  unsigned* bind = (unsigned*)t3b;   // NB*CAPB*4 = 8.45MB <= 12.8MB
  int*      bins = (int*)t4b;

  hipMemsetAsync(gcd, 0, (size_t)NB * 4, stream);
  hipMemsetAsync(gcs, 0, (size_t)NB * 4, stream);

  binA_kernel<<<NE / EPB, ABD, 0, stream>>>(ei, gcd, gcs, bind, bins);
  binB_kernel<<<NB, 256, 0, stream>>>(bind, bins, gcd, gcs, cnt, isq, col);
  cast_kernel<<<(NN * DD / 8 + 255) / 256, 256, 0, stream>>>(x, xb);
  prep_kernel<<<18, 256, 0, stream>>>(cw, w1, w2, w3, w4, wf);

  // 8 nodes per wave: 12500 waves = 3125 blocks exactly; all-bf16 state
  prop_kernel<<<NN / 32, 256, 0, stream>>>(xb,  xb,  t1b, cnt, col, isq, 0);
  prop_kernel<<<NN / 32, 256, 0, stream>>>(t1b, xb,  t2b, cnt, col, isq, 1);
  prop_kernel<<<NN / 32, 256, 0, stream>>>(t2b, t1b, t3b, cnt, col, isq, 1);
  prop_kernel<<<NN / 32, 256, 0, stream>>>(t3b, t2b, t4b, cnt, col, isq, 1);

  dense_kernel<<<(NN + 255) / 256, 256, 0, stream>>>(xb, t1b, t2b, t3b, t4b, wf,
                                                     cb, b1, b2, b3, b4, lng, lnb, out);
}